// Round 1
// baseline (190.962 us; speedup 1.0000x reference)
//
#include <hip/hip_runtime.h>
#include <math.h>
#include <float.h>

// ws layout (ints): [0 .. B] = start offsets (B+1), [B+1] = batch element stride (1=int32, 2=int64)

__global__ void detect_kernel(const int* __restrict__ words, int N, int* __restrict__ meta) {
    // batch is sorted, non-negative, last value ~B-1 (>0 w.p. ~1). If stored as
    // little-endian int64, word (N-1) is the HIGH half of element (N-2)/2 => 0.
    // If int32, word (N-1) is the last value => nonzero.
    meta[0] = (words[(size_t)N - 1] != 0) ? 1 : 2;
}

__global__ void starts_kernel(const int* __restrict__ words, int N, int B,
                              int* __restrict__ start, const int* __restrict__ meta) {
    int i = blockIdx.x * blockDim.x + threadIdx.x;
    if (i >= N) return;
    const int stride = meta[0];  // broadcast, L2-cached
    int cur = words[(size_t)i * stride];
    if (i == 0) {
        for (int b = 0; b <= cur; ++b) start[b] = 0;
    } else {
        int prev = words[(size_t)(i - 1) * stride];
        if (prev != cur) {
            for (int b = prev + 1; b <= cur; ++b) start[b] = i;
        }
    }
    if (i == N - 1) {
        for (int b = cur + 1; b <= B; ++b) start[b] = N;
    }
}

// D = 128 fixed (32 float4 per row). 256 threads = 8 row-groups x 32 quad-lanes.
__global__ __launch_bounds__(256) void pool_kernel(const float4* __restrict__ x,
                                                   const int* __restrict__ start,
                                                   const float* __restrict__ alpha,
                                                   float4* __restrict__ out) {
    const int b  = blockIdx.x;
    const int t  = threadIdx.x;
    const int c4 = t & 31;   // which float4 of the 128-col row
    const int rg = t >> 5;   // row group 0..7

    const int s = start[b];
    const int e = start[b + 1];

    float4 sum = make_float4(0.f, 0.f, 0.f, 0.f);
    float4 mx  = make_float4(-FLT_MAX, -FLT_MAX, -FLT_MAX, -FLT_MAX);

    for (int r = s + rg; r < e; r += 8) {
        float4 v = x[(size_t)r * 32 + c4];
        sum.x += v.x; sum.y += v.y; sum.z += v.z; sum.w += v.w;
        mx.x = fmaxf(mx.x, v.x); mx.y = fmaxf(mx.y, v.y);
        mx.z = fmaxf(mx.z, v.z); mx.w = fmaxf(mx.w, v.w);
    }

    __shared__ float4 lsum[8][32];
    __shared__ float4 lmax[8][32];
    lsum[rg][c4] = sum;
    lmax[rg][c4] = mx;
    __syncthreads();

    if (rg == 0) {
        #pragma unroll
        for (int r = 1; r < 8; ++r) {
            float4 ps = lsum[r][c4];
            float4 pm = lmax[r][c4];
            sum.x += ps.x; sum.y += ps.y; sum.z += ps.z; sum.w += ps.w;
            mx.x = fmaxf(mx.x, pm.x); mx.y = fmaxf(mx.y, pm.y);
            mx.z = fmaxf(mx.z, pm.z); mx.w = fmaxf(mx.w, pm.w);
        }
        const int cnt = e - s;
        float a = 1.0f / (1.0f + __expf(-alpha[0]));
        float4 o;
        if (cnt == 0) {
            o = make_float4(0.f, 0.f, 0.f, 0.f);
        } else {
            float inv = 1.0f / (float)cnt;
            float ia = 1.0f - a;
            o.x = a * (sum.x * inv) + ia * mx.x;
            o.y = a * (sum.y * inv) + ia * mx.y;
            o.z = a * (sum.z * inv) + ia * mx.z;
            o.w = a * (sum.w * inv) + ia * mx.w;
        }
        out[(size_t)b * 32 + c4] = o;
    }
}

extern "C" void kernel_launch(void* const* d_in, const int* in_sizes, int n_in,
                              void* d_out, int out_size, void* d_ws, size_t ws_size,
                              hipStream_t stream) {
    const float* x     = (const float*)d_in[0];
    const int*   batch = (const int*)d_in[1];   // stride-detected (int32 vs int64)
    const float* alpha = (const float*)d_in[2];

    const int N = in_sizes[1];              // 2,000,000
    const int Dd = in_sizes[0] / N;         // 128
    const int B = out_size / Dd;            // 4096

    int* ws_start = (int*)d_ws;             // B+1 ints
    int* ws_meta  = ws_start + (B + 1);     // 1 int

    detect_kernel<<<1, 1, 0, stream>>>(batch, N, ws_meta);

    int threads = 256;
    int blocks = (N + threads - 1) / threads;
    starts_kernel<<<blocks, threads, 0, stream>>>(batch, N, B, ws_start, ws_meta);

    pool_kernel<<<B, 256, 0, stream>>>((const float4*)x, ws_start, alpha,
                                       (float4*)d_out);
}

// Round 2
// 163.881 us; speedup vs baseline: 1.1653x; 1.1653x over previous
//
#include <hip/hip_runtime.h>
#include <math.h>
#include <float.h>

typedef float f32x4 __attribute__((ext_vector_type(4)));

__device__ __forceinline__ f32x4 max4(f32x4 a, f32x4 b) {
    f32x4 r;
    r.x = fmaxf(a.x, b.x); r.y = fmaxf(a.y, b.y);
    r.z = fmaxf(a.z, b.z); r.w = fmaxf(a.w, b.w);
    return r;
}

// One block per segment. batch is SORTED -> per-block binary search for [s,e).
// 256 threads = 8 row-groups x 32 float4-lanes; 2x unrolled streaming loop.
__global__ __launch_bounds__(256) void pool_kernel(const f32x4* __restrict__ x,
                                                   const int* __restrict__ words, int N,
                                                   const float* __restrict__ alpha,
                                                   f32x4* __restrict__ out) {
    const int b  = blockIdx.x;
    const int t  = threadIdx.x;
    const int c4 = t & 31;   // float4 column 0..31
    const int rg = t >> 5;   // row group 0..7

    // int32 vs int64 storage detect: for int64 (little-endian), word N-1 is a
    // high half of a small value -> 0; for int32 it's the last batch id != 0.
    const int stride = (words[(size_t)N - 1] != 0) ? 1 : 2;

    // lower_bound(b)
    int lo = 0, hi = N;
    while (lo < hi) {
        int mid = (lo + hi) >> 1;
        if (words[(size_t)mid * stride] < b) lo = mid + 1; else hi = mid;
    }
    const int s = lo;
    // lower_bound(b+1), starting from s
    hi = N;
    while (lo < hi) {
        int mid = (lo + hi) >> 1;
        if (words[(size_t)mid * stride] < b + 1) lo = mid + 1; else hi = mid;
    }
    const int e = lo;

    f32x4 sum0 = (f32x4)0.f, sum1 = (f32x4)0.f;
    f32x4 mx0 = (f32x4)(-FLT_MAX), mx1 = (f32x4)(-FLT_MAX);

    const f32x4* __restrict__ xp = x + c4;
    int r = s + rg;
    for (; r + 8 < e; r += 16) {
        f32x4 v0 = __builtin_nontemporal_load(xp + (size_t)r * 32);
        f32x4 v1 = __builtin_nontemporal_load(xp + (size_t)(r + 8) * 32);
        sum0 += v0; mx0 = max4(mx0, v0);
        sum1 += v1; mx1 = max4(mx1, v1);
    }
    if (r < e) {
        f32x4 v0 = __builtin_nontemporal_load(xp + (size_t)r * 32);
        sum0 += v0; mx0 = max4(mx0, v0);
    }
    sum0 += sum1;
    mx0 = max4(mx0, mx1);

    __shared__ f32x4 lsum[8][32];
    __shared__ f32x4 lmax[8][32];
    lsum[rg][c4] = sum0;
    lmax[rg][c4] = mx0;
    __syncthreads();

    if (rg == 0) {
        #pragma unroll
        for (int k = 1; k < 8; ++k) {
            sum0 += lsum[k][c4];
            mx0 = max4(mx0, lmax[k][c4]);
        }
        const int cnt = e - s;
        const float a = 1.0f / (1.0f + __expf(-alpha[0]));
        f32x4 o;
        if (cnt == 0) {
            o = (f32x4)0.f;
        } else {
            const float inv = 1.0f / (float)cnt;
            const float ia = 1.0f - a;
            o = a * (sum0 * inv) + ia * mx0;
        }
        out[(size_t)b * 32 + c4] = o;
    }
}

extern "C" void kernel_launch(void* const* d_in, const int* in_sizes, int n_in,
                              void* d_out, int out_size, void* d_ws, size_t ws_size,
                              hipStream_t stream) {
    const float* x     = (const float*)d_in[0];
    const int*   batch = (const int*)d_in[1];   // int32-or-int64, stride-detected
    const float* alpha = (const float*)d_in[2];

    const int N = in_sizes[1];          // 2,000,000
    const int D = in_sizes[0] / N;      // 128
    const int B = out_size / D;         // 4096
    (void)d_ws; (void)ws_size; (void)n_in;

    pool_kernel<<<B, 256, 0, stream>>>((const f32x4*)x, batch, N, alpha,
                                       (f32x4*)d_out);
}